// Round 5
// baseline (805.816 us; speedup 1.0000x reference)
//
#include <hip/hip_runtime.h>

// Shapes (fixed by the reference)
#define BB 8
#define SS 1024
#define DD 1024
#define HH 16
#define DK 64
#define FF 4096
#define MM (BB*SS)   // 8192

typedef __attribute__((ext_vector_type(8))) short short8;
typedef __attribute__((ext_vector_type(4))) short short4v;
typedef __attribute__((ext_vector_type(4))) float floatx4;

__device__ inline short f2bf(float f) {
  union { float f; unsigned u; } v; v.f = f;
  unsigned r = (v.u + 0x7FFFu + ((v.u >> 16) & 1u)) >> 16;
  return (short)r;
}
__device__ inline float bf2f(unsigned short u) {
  union { unsigned u; float f; } v; v.u = ((unsigned)u) << 16;
  return v.f;
}

// async global->LDS, 16B per lane; lds dst must be wave-uniform base (+lane*16)
__device__ inline void gload_lds16(const void* g, void* l) {
  __builtin_amdgcn_global_load_lds(
      (const __attribute__((address_space(1))) void*)g,
      (__attribute__((address_space(3))) void*)l, 16, 0, 0);
}

// ---------------------------------------------------------------------------
// fp32 -> bf16 elementwise (8 per thread)
// ---------------------------------------------------------------------------
__global__ __launch_bounds__(256) void cvt_bf16(
    const float* __restrict__ in, unsigned short* __restrict__ out, int n) {
  int i8 = (blockIdx.x * 256 + threadIdx.x) * 8;
  if (i8 >= n) return;
  float4 a = *(const float4*)(in + i8);
  float4 b = *(const float4*)(in + i8 + 4);
  short8 o;
  o[0] = f2bf(a.x); o[1] = f2bf(a.y); o[2] = f2bf(a.z); o[3] = f2bf(a.w);
  o[4] = f2bf(b.x); o[5] = f2bf(b.y); o[6] = f2bf(b.z); o[7] = f2bf(b.w);
  *(short8*)(out + i8) = o;
}

// ---------------------------------------------------------------------------
// Build WqkvT [3072,1024] bf16: WqkvT[z*1024+h*64+dk][d] = Wz[h][d][dk].
// ---------------------------------------------------------------------------
__global__ __launch_bounds__(256) void prep_wqkv(
    const float* __restrict__ Wq, const float* __restrict__ Wk,
    const float* __restrict__ Wv, unsigned short* __restrict__ wt) {
  const int d0 = blockIdx.x * 64, h = blockIdx.y, z = blockIdx.z;
  const float* W = (z == 0 ? Wq : z == 1 ? Wk : Wv) + (size_t)h * DD * DK;
  __shared__ float ld[64][68];
  const int tid = threadIdx.x;
  {
    int r = tid >> 2, c16 = (tid & 3) * 16;
#pragma unroll
    for (int i = 0; i < 4; ++i)
      *(float4*)(&ld[r][c16 + i * 4]) = *(const float4*)(W + (size_t)(d0 + r) * DK + c16 + i * 4);
  }
  __syncthreads();
  int dv = tid >> 2, d16 = (tid & 3) * 16;
  short8 o0, o1;
#pragma unroll
  for (int i = 0; i < 8; ++i) {
    o0[i] = f2bf(ld[d16 + i][dv]);
    o1[i] = f2bf(ld[d16 + 8 + i][dv]);
  }
  unsigned short* dst = wt + (size_t)(z * 1024 + h * 64 + dv) * DD + d0 + d16;
  *(short8*)(dst) = o0;
  *(short8*)(dst + 8) = o1;
}

__global__ __launch_bounds__(256) void prep_bias(
    const float* __restrict__ bq, const float* __restrict__ bk,
    const float* __restrict__ bv, float* __restrict__ bqkv) {
  int n = blockIdx.x * 256 + threadIdx.x;   // 0..3071
  int z = n >> 10;
  const float* s = (z == 0 ? bq : z == 1 ? bk : bv);
  bqkv[n] = s[n & 1023];
}

// ---------------------------------------------------------------------------
// Generic transpose fp32 [R][C] -> bf16 [C][R]. grid (R/64, C/64), block 256.
// ---------------------------------------------------------------------------
__global__ __launch_bounds__(256) void transpose_w(
    const float* __restrict__ src, unsigned short* __restrict__ dst,
    int R, int C) {
  const int r0 = blockIdx.x * 64, c0 = blockIdx.y * 64;
  __shared__ float ld[64][68];
  const int tid = threadIdx.x;
  {
    int r = tid >> 2, c16 = (tid & 3) * 16;
#pragma unroll
    for (int i = 0; i < 4; ++i)
      *(float4*)(&ld[r][c16 + i * 4]) =
          *(const float4*)(src + (size_t)(r0 + r) * C + c0 + c16 + i * 4);
  }
  __syncthreads();
  int c = tid >> 2, r16 = (tid & 3) * 16;
  short8 o0, o1;
#pragma unroll
  for (int i = 0; i < 8; ++i) {
    o0[i] = f2bf(ld[r16 + i][c]);
    o1[i] = f2bf(ld[r16 + 8 + i][c]);
  }
  unsigned short* d = dst + (size_t)(c0 + c) * R + r0 + r16;
  *(short8*)(d) = o0;
  *(short8*)(d + 8) = o1;
}

// ---------------------------------------------------------------------------
// V transpose from qkv buffer: vt[b,h,dv,t] = qkv[(b*S+t)*3072 + 2048 + h*64 + dv]
// ---------------------------------------------------------------------------
__global__ __launch_bounds__(256) void transpose_v(
    const unsigned short* __restrict__ qkv, unsigned short* __restrict__ vt) {
  const int t0 = blockIdx.x * 64, h = blockIdx.y, b = blockIdx.z;
  __shared__ unsigned short ld[64][72];
  const int tid = threadIdx.x;
  {
    int r = tid >> 2, c16 = (tid & 3) * 16;
    const unsigned short* s = qkv + (size_t)(b * SS + t0 + r) * 3072 + 2048 + h * 64 + c16;
    *(short8*)(&ld[r][c16]) = *(const short8*)(s);
    *(short8*)(&ld[r][c16 + 8]) = *(const short8*)(s + 8);
  }
  __syncthreads();
  int dv = tid >> 2, t16 = (tid & 3) * 16;
  short8 o0, o1;
#pragma unroll
  for (int i = 0; i < 8; ++i) {
    o0[i] = (short)ld[t16 + i][dv];
    o1[i] = (short)ld[t16 + 8 + i][dv];
  }
  unsigned short* d = vt + ((size_t)(b * HH + h) * DK + dv) * SS + t0 + t16;
  *(short8*)(d) = o0;
  *(short8*)(d + 8) = o1;
}

// ---------------------------------------------------------------------------
// bf16 MFMA GEMM (m97 structure): C[M,N] = A[M,K] @ B[K,N] + bias (+ReLU).
// Operand-SWAPPED mfma (bf first) so each lane's 4 acc regs are 4 consecutive
// N-cols -> b64 epilogue stores + float4 bias loads.
// ---------------------------------------------------------------------------
template <int RELU>
__global__ __launch_bounds__(256) void gemm_bf16(
    const unsigned short* __restrict__ A, const unsigned short* __restrict__ Bt,
    const float* __restrict__ bias, unsigned short* __restrict__ C,
    int M, int N, int K) {
  const int n0 = blockIdx.x * 128, m0 = blockIdx.y * 128;
  __shared__ __align__(16) unsigned short As[128 * 32];
  __shared__ __align__(16) unsigned short Bs[128 * 32];
  const int tid = threadIdx.x;
  const int wave = tid >> 6, lane = tid & 63;
  const int lm = lane & 15, quad = lane >> 4;
  const int wr = wave >> 1, wc = wave & 1;
  const int srow = lane >> 2;        // 0..15 (staging row within 16-row chunk)
  const int scol = (lane & 3) * 8;   // bf16 offset within row (16B granules)

  floatx4 acc[4][4] = {};

  for (int k0 = 0; k0 < K; k0 += 32) {
#pragma unroll
    for (int j = 0; j < 2; ++j) {
      int rr = wave * 32 + j * 16;
      gload_lds16(A + (size_t)(m0 + rr + srow) * K + k0 + scol, &As[rr * 32]);
      gload_lds16(Bt + (size_t)(n0 + rr + srow) * K + k0 + scol, &Bs[rr * 32]);
    }
    __syncthreads();
    short8 af[4], bf[4];
#pragma unroll
    for (int i = 0; i < 4; ++i)
      af[i] = *(const short8*)&As[(wr * 64 + i * 16 + lm) * 32 + quad * 8];
#pragma unroll
    for (int j = 0; j < 4; ++j)
      bf[j] = *(const short8*)&Bs[(wc * 64 + j * 16 + lm) * 32 + quad * 8];
#pragma unroll
    for (int i = 0; i < 4; ++i)
#pragma unroll
      for (int j = 0; j < 4; ++j)
        acc[i][j] = __builtin_amdgcn_mfma_f32_16x16x32_bf16(bf[j], af[i], acc[i][j], 0, 0, 0);
    __syncthreads();
  }

  // lane holds C[row = m0+wr*64+i*16+lm][col = n0+wc*64+j*16+quad*4 + r]
#pragma unroll
  for (int i = 0; i < 4; ++i) {
    const int row = m0 + wr * 64 + i * 16 + lm;
#pragma unroll
    for (int j = 0; j < 4; ++j) {
      const int c0 = n0 + wc * 64 + j * 16 + quad * 4;
      float4 bv = *(const float4*)(bias + c0);
      float bb[4] = {bv.x, bv.y, bv.z, bv.w};
      short4v o;
#pragma unroll
      for (int r = 0; r < 4; ++r) {
        float v = acc[i][j][r] + bb[r];
        if (RELU) v = fmaxf(v, 0.f);
        o[r] = f2bf(v);
      }
      *(short4v*)(C + (size_t)row * N + c0) = o;
    }
  }
}

// ---------------------------------------------------------------------------
// MFMA attention v2. 16 q-rows per block, 256 thr = 4 waves.
// Pass A (swapped mfma -> regs along t): P[qrow][t] = logits/8 (mask deferred),
//   one ds_write_b64 per step; running per-lane row-max -> wave max via shfl.
// Pass B: coalesced mask float4 + exp + sum in one pass (no max scan).
// Pass C: ctx^T = V^T @ P^T, b64 ctx store.
// ---------------------------------------------------------------------------
__global__ __launch_bounds__(256) void attention_mfma(
    const unsigned short* __restrict__ qkv, const unsigned short* __restrict__ vt,
    const float* __restrict__ mask, unsigned short* __restrict__ ctx) {
  const int s0 = blockIdx.x * 16;
  const int h = blockIdx.y, b = blockIdx.z;
  const int tid = threadIdx.x;
  const int wave = tid >> 6, lane = tid & 63;
  const int lm = lane & 15, quad = lane >> 4;

  __shared__ unsigned short P[16 * 1032];  // 33 KB logits/P strip
  __shared__ float wmax[4][16];            // per-wave-strip row max
  __shared__ float rs[16];                 // 1/rowsum

  const unsigned short* qp = qkv + (size_t)(b * SS + s0 + lm) * 3072 + h * 64;
  const short8 qa0 = *(const short8*)(qp + quad * 8);
  const short8 qa1 = *(const short8*)(qp + quad * 8 + 32);

  // ---- pass A: logits (swapped: D[t][qrow], lane col = qrow lm, regs = t) ----
  float rmax = -3e38f;
  for (int jt = 0; jt < 16; ++jt) {
    const int t0 = wave * 256 + jt * 16;
    const unsigned short* kp = qkv + (size_t)(b * SS + t0 + lm) * 3072 + 1024 + h * 64;
    short8 kb0 = *(const short8*)(kp + quad * 8);
    short8 kb1 = *(const short8*)(kp + quad * 8 + 32);
    floatx4 c = {0.f, 0.f, 0.f, 0.f};
    c = __builtin_amdgcn_mfma_f32_16x16x32_bf16(kb0, qa0, c, 0, 0, 0);
    c = __builtin_amdgcn_mfma_f32_16x16x32_bf16(kb1, qa1, c, 0, 0, 0);
    short4v o;
#pragma unroll
    for (int r = 0; r < 4; ++r) {
      float sv = c[r] * 0.125f;      // logit for (qrow=lm, t=t0+quad*4+r)
      rmax = fmaxf(rmax, sv);
      o[r] = f2bf(sv);
    }
    *(short4v*)(P + lm * 1032 + t0 + quad * 4) = o;
  }
  // combine across quads (lanes lm, lm+16, lm+32, lm+48 hold row lm slices)
  rmax = fmaxf(rmax, __shfl_xor(rmax, 16));
  rmax = fmaxf(rmax, __shfl_xor(rmax, 32));
  if (lane < 16) wmax[wave][lm] = rmax;
  __syncthreads();

  // ---- pass B: mask + exp + sum (rows wave*4 .. wave*4+3) ----
#pragma unroll
  for (int ri = 0; ri < 4; ++ri) {
    const int row = wave * 4 + ri;
    const float gmax = fmaxf(fmaxf(wmax[0][row], wmax[1][row]),
                             fmaxf(wmax[2][row], wmax[3][row]));
    unsigned short* prow = P + row * 1032 + lane * 16;
    const float* mrow = mask + (size_t)(s0 + row) * SS + lane * 16;
    short8 x0 = *(short8*)(prow);
    short8 x1 = *(short8*)(prow + 8);
    float m[16];
#pragma unroll
    for (int g = 0; g < 4; ++g) {
      float4 mv = *(const float4*)(mrow + g * 4);
      m[g * 4 + 0] = mv.x; m[g * 4 + 1] = mv.y;
      m[g * 4 + 2] = mv.z; m[g * 4 + 3] = mv.w;
    }
    float sm = 0.f;
#pragma unroll
    for (int i = 0; i < 8; ++i) {
      float f0 = __expf(bf2f((unsigned short)x0[i]) + m[i] * (-1e9f) - gmax);
      float f1 = __expf(bf2f((unsigned short)x1[i]) + m[8 + i] * (-1e9f) - gmax);
      sm += f0 + f1;
      x0[i] = f2bf(f0);
      x1[i] = f2bf(f1);
    }
#pragma unroll
    for (int o = 1; o < 64; o <<= 1) sm += __shfl_xor(sm, o);
    *(short8*)(prow) = x0;
    *(short8*)(prow + 8) = x1;
    if (lane == 0) rs[row] = 1.f / sm;
  }
  __syncthreads();

  // ---- pass C: ctx^T = V^T @ P^T; wave handles dv-tile [wave*16, wave*16+16) ----
  const int dv0 = wave * 16;
  const size_t vbase = (size_t)(b * HH + h) * DK * SS;
  const unsigned short* vrow = vt + vbase + (size_t)(dv0 + lm) * SS;
  floatx4 acc = {0.f, 0.f, 0.f, 0.f};
  for (int jt = 0; jt < 16; ++jt) {
    const int t0 = jt * 64;
    short8 va0 = *(const short8*)(vrow + t0 + quad * 8);
    short8 pb0 = *(const short8*)(P + lm * 1032 + t0 + quad * 8);
    acc = __builtin_amdgcn_mfma_f32_16x16x32_bf16(va0, pb0, acc, 0, 0, 0);
    short8 va1 = *(const short8*)(vrow + t0 + 32 + quad * 8);
    short8 pb1 = *(const short8*)(P + lm * 1032 + t0 + 32 + quad * 8);
    acc = __builtin_amdgcn_mfma_f32_16x16x32_bf16(va1, pb1, acc, 0, 0, 0);
  }
  const float sc = rs[lm];
  short4v o;
#pragma unroll
  for (int r = 0; r < 4; ++r) o[r] = f2bf(acc[r] * sc);
  *(short4v*)(ctx + (size_t)(b * SS + s0 + lm) * DD + h * DK + dv0 + quad * 4) = o;
}

// ---------------------------------------------------------------------------
// Residual + LayerNorm: out = LN(a + r) * w + b. One block per row (D=1024).
// ---------------------------------------------------------------------------
template <int A_BF16, int OUT_BF16>
__global__ __launch_bounds__(256) void residual_ln(
    const void* __restrict__ a_, const unsigned short* __restrict__ rr,
    const float* __restrict__ w, const float* __restrict__ bias,
    void* __restrict__ out_) {
  const int row = blockIdx.x;
  const int t = threadIdx.x;
  float x[4];
  if (A_BF16) {
    short4v va = *(const short4v*)((const unsigned short*)a_ + (size_t)row * DD + t * 4);
#pragma unroll
    for (int i = 0; i < 4; ++i) x[i] = bf2f((unsigned short)va[i]);
  } else {
    float4 va = *(const float4*)((const float*)a_ + (size_t)row * DD + t * 4);
    x[0] = va.x; x[1] = va.y; x[2] = va.z; x[3] = va.w;
  }
  {
    short4v vr = *(const short4v*)(rr + (size_t)row * DD + t * 4);
#pragma unroll
    for (int i = 0; i < 4; ++i) x[i] += bf2f((unsigned short)vr[i]);
  }
  float s = 0.f, ss = 0.f;
#pragma unroll
  for (int i = 0; i < 4; ++i) { s += x[i]; ss += x[i] * x[i]; }
#pragma unroll
  for (int o = 32; o > 0; o >>= 1) {
    s  += __shfl_down(s, o);
    ss += __shfl_down(ss, o);
  }
  __shared__ float2 sred[4];
  int wid = t >> 6;
  if ((t & 63) == 0) sred[wid] = make_float2(s, ss);
  __syncthreads();
  float st = 0.f, sst = 0.f;
#pragma unroll
  for (int i = 0; i < 4; ++i) { st += sred[i].x; sst += sred[i].y; }
  float mu  = st * (1.f / 1024.f);
  float var = sst * (1.f / 1024.f) - mu * mu;
  float rsq = rsqrtf(var + 1e-5f);
  float4 vw = *(const float4*)(w + t * 4);
  float4 vb = *(const float4*)(bias + t * 4);
  float o[4];
  o[0] = (x[0] - mu) * rsq * vw.x + vb.x;
  o[1] = (x[1] - mu) * rsq * vw.y + vb.y;
  o[2] = (x[2] - mu) * rsq * vw.z + vb.z;
  o[3] = (x[3] - mu) * rsq * vw.w + vb.w;
  if (OUT_BF16) {
    short4v ov;
#pragma unroll
    for (int i = 0; i < 4; ++i) ov[i] = f2bf(o[i]);
    *(short4v*)((unsigned short*)out_ + (size_t)row * DD + t * 4) = ov;
  } else {
    float4 ov = {o[0], o[1], o[2], o[3]};
    *(float4*)((float*)out_ + (size_t)row * DD + t * 4) = ov;
  }
}

// ---------------------------------------------------------------------------
extern "C" void kernel_launch(void* const* d_in, const int* in_sizes, int n_in,
                              void* d_out, int out_size, void* d_ws, size_t ws_size,
                              hipStream_t stream) {
  const float* src  = (const float*)d_in[0];
  const float* mask = (const float*)d_in[1];
  const float* Wq = (const float*)d_in[2];  const float* bq = (const float*)d_in[3];
  const float* Wk = (const float*)d_in[4];  const float* bk = (const float*)d_in[5];
  const float* Wv = (const float*)d_in[6];  const float* bv = (const float*)d_in[7];
  const float* Wo = (const float*)d_in[8];  const float* bo = (const float*)d_in[9];
  const float* ln1w = (const float*)d_in[10]; const float* ln1b = (const float*)d_in[11];
  const float* W1 = (const float*)d_in[12]; const float* b1 = (const float*)d_in[13];
  const float* W2 = (const float*)d_in[14]; const float* b2 = (const float*)d_in[15];
  const float* ln2w = (const float*)d_in[16]; const float* ln2b = (const float*)d_in[17];
  float* out = (float*)d_out;

  // Workspace layout (byte offsets), total 125,841,408 B (~120 MiB):
  //  [  0, 48M)  qkv bf16 [M,3072]          -> h1 bf16 [M,4096] (after LN1)
  //  [ 48, 64M)  vt bf16 [B,H,DK,S]         -> attn_out bf16 (after attention)
  //  [ 64, 80M)  ctx bf16 [M,1024]          -> xb bf16 (after Wo gemm)
  //  [ 80, 96M)  srcb bf16 [M,1024]         -> ffn bf16 (after QKV gemm)
  //  [ 96,120M)  weights: wqkvT, woT, w1T, w2T, bqkv
  const size_t NEED = 125841408;
  if (ws_size < NEED) return;

  char* ws = (char*)d_ws;
  unsigned short* qkv   = (unsigned short*)(ws);
  unsigned short* vtb   = (unsigned short*)(ws + 50331648);
  unsigned short* ctxb  = (unsigned short*)(ws + 67108864);
  unsigned short* srcb  = (unsigned short*)(ws + 83886080);
  unsigned short* wqkvT = (unsigned short*)(ws + 100663296);  // [3072,1024]
  unsigned short* woT   = (unsigned short*)(ws + 106954752);  // [1024,1024]
  unsigned short* w1T   = (unsigned short*)(ws + 109051904);  // [4096,1024]
  unsigned short* w2T   = (unsigned short*)(ws + 117440512);  // [1024,4096]
  float*          bqkv  = (float*)(ws + 125829120);           // [3072]
  unsigned short* h1       = qkv;   // [M,4096] spans qkv+vtb
  unsigned short* attn_out = vtb;
  unsigned short* xb       = ctxb;
  unsigned short* ffn      = srcb;

  // ---- prep (bf16 casts + weight transposes) ----
  cvt_bf16<<<MM * DD / (256 * 8), 256, 0, stream>>>(src, srcb, MM * DD);
  prep_wqkv<<<dim3(DD / 64, HH, 3), 256, 0, stream>>>(Wq, Wk, Wv, wqkvT);
  prep_bias<<<12, 256, 0, stream>>>(bq, bk, bv, bqkv);
  transpose_w<<<dim3(16, 16), 256, 0, stream>>>(Wo, woT, 1024, 1024);
  transpose_w<<<dim3(16, 64), 256, 0, stream>>>(W1, w1T, 1024, 4096);
  transpose_w<<<dim3(64, 16), 256, 0, stream>>>(W2, w2T, 4096, 1024);

  // ---- main pipeline ----
  gemm_bf16<0><<<dim3(3072 / 128, MM / 128), 256, 0, stream>>>(srcb, wqkvT, bqkv, qkv, MM, 3072, DD);
  transpose_v<<<dim3(SS / 64, HH, BB), 256, 0, stream>>>(qkv, vtb);
  attention_mfma<<<dim3(SS / 16, HH, BB), 256, 0, stream>>>(qkv, vtb, mask, ctxb);
  gemm_bf16<0><<<dim3(DD / 128, MM / 128), 256, 0, stream>>>(ctxb, woT, bo, attn_out, MM, DD, DD);
  residual_ln<0, 1><<<MM, 256, 0, stream>>>(src, attn_out, ln1w, ln1b, xb);
  gemm_bf16<1><<<dim3(FF / 128, MM / 128), 256, 0, stream>>>(xb, w1T, b1, h1, MM, FF, DD);
  gemm_bf16<0><<<dim3(DD / 128, MM / 128), 256, 0, stream>>>(h1, w2T, b2, ffn, MM, DD, FF);
  residual_ln<1, 0><<<MM, 256, 0, stream>>>(xb, ffn, ln2w, ln2b, out);
}

// Round 6
// 783.708 us; speedup vs baseline: 1.0282x; 1.0282x over previous
//
#include <hip/hip_runtime.h>

// Shapes (fixed by the reference)
#define BB 8
#define SS 1024
#define DD 1024
#define HH 16
#define DK 64
#define FF 4096
#define MM (BB*SS)   // 8192

typedef __attribute__((ext_vector_type(8))) short short8;
typedef __attribute__((ext_vector_type(4))) short short4v;
typedef __attribute__((ext_vector_type(4))) float floatx4;

__device__ inline short f2bf(float f) {
  union { float f; unsigned u; } v; v.f = f;
  unsigned r = (v.u + 0x7FFFu + ((v.u >> 16) & 1u)) >> 16;
  return (short)r;
}
__device__ inline float bf2f(unsigned short u) {
  union { unsigned u; float f; } v; v.u = ((unsigned)u) << 16;
  return v.f;
}

// async global->LDS, 16B per lane; lds dst must be wave-uniform base (+lane*16)
__device__ inline void gload_lds16(const void* g, void* l) {
  __builtin_amdgcn_global_load_lds(
      (const __attribute__((address_space(1))) void*)g,
      (__attribute__((address_space(3))) void*)l, 16, 0, 0);
}

// ---------------------------------------------------------------------------
// Fused prep kernel (flat grid, 256 thr):
//  [0,4096)      cvt src fp32 -> bf16 (srcb)
//  [4096,4864)   WqkvT [3072,1024]: WqkvT[z*1024+h*64+dk][d] = Wz[h][d][dk]
//  [4864,4876)   bqkv concat
//  [4876,5132)   WoT  [1024,1024]
//  [5132,6156)   W1T  [4096,1024]
//  [6156,7180)   W2T  [1024,4096]
// ---------------------------------------------------------------------------
__device__ void tr64(const float* __restrict__ s, unsigned short* __restrict__ d,
                     int R, int C, int r0, int c0, float (*ld)[68], int tid) {
  {
    int r = tid >> 2, c16 = (tid & 3) * 16;
#pragma unroll
    for (int i = 0; i < 4; ++i)
      *(float4*)(&ld[r][c16 + i * 4]) =
          *(const float4*)(s + (size_t)(r0 + r) * C + c0 + c16 + i * 4);
  }
  __syncthreads();
  int c = tid >> 2, r16 = (tid & 3) * 16;
  short8 o0, o1;
#pragma unroll
  for (int i = 0; i < 8; ++i) {
    o0[i] = f2bf(ld[r16 + i][c]);
    o1[i] = f2bf(ld[r16 + 8 + i][c]);
  }
  unsigned short* dp = d + (size_t)(c0 + c) * R + r0 + r16;
  *(short8*)(dp) = o0;
  *(short8*)(dp + 8) = o1;
}

__global__ __launch_bounds__(256) void prep_all(
    const float* __restrict__ src,
    const float* __restrict__ Wq, const float* __restrict__ Wk,
    const float* __restrict__ Wv,
    const float* __restrict__ bq, const float* __restrict__ bk,
    const float* __restrict__ bv,
    const float* __restrict__ Wo, const float* __restrict__ W1,
    const float* __restrict__ W2,
    unsigned short* __restrict__ srcb, unsigned short* __restrict__ wqkvT,
    float* __restrict__ bqkv, unsigned short* __restrict__ woT,
    unsigned short* __restrict__ w1T, unsigned short* __restrict__ w2T) {
  __shared__ float ld[64][68];
  const int bid = blockIdx.x, tid = threadIdx.x;
  if (bid < 4096) {
    int i8 = (bid * 256 + tid) * 8;
    float4 a = *(const float4*)(src + i8);
    float4 b = *(const float4*)(src + i8 + 4);
    short8 o;
    o[0] = f2bf(a.x); o[1] = f2bf(a.y); o[2] = f2bf(a.z); o[3] = f2bf(a.w);
    o[4] = f2bf(b.x); o[5] = f2bf(b.y); o[6] = f2bf(b.z); o[7] = f2bf(b.w);
    *(short8*)(srcb + i8) = o;
  } else if (bid < 4864) {
    int idx = bid - 4096;
    int d0 = (idx & 15) * 64, h = (idx >> 4) & 15, z = idx >> 8;
    const float* W = (z == 0 ? Wq : z == 1 ? Wk : Wv) + (size_t)h * DD * DK;
    {
      int r = tid >> 2, c16 = (tid & 3) * 16;
#pragma unroll
      for (int i = 0; i < 4; ++i)
        *(float4*)(&ld[r][c16 + i * 4]) =
            *(const float4*)(W + (size_t)(d0 + r) * DK + c16 + i * 4);
    }
    __syncthreads();
    int dv = tid >> 2, d16 = (tid & 3) * 16;
    short8 o0, o1;
#pragma unroll
    for (int i = 0; i < 8; ++i) {
      o0[i] = f2bf(ld[d16 + i][dv]);
      o1[i] = f2bf(ld[d16 + 8 + i][dv]);
    }
    unsigned short* dst = wqkvT + (size_t)(z * 1024 + h * 64 + dv) * DD + d0 + d16;
    *(short8*)(dst) = o0;
    *(short8*)(dst + 8) = o1;
  } else if (bid < 4876) {
    int n = (bid - 4864) * 256 + tid;   // 0..3071
    int z = n >> 10;
    const float* s = (z == 0 ? bq : z == 1 ? bk : bv);
    bqkv[n] = s[n & 1023];
  } else if (bid < 5132) {
    int idx = bid - 4876;
    tr64(Wo, woT, 1024, 1024, (idx & 15) * 64, (idx >> 4) * 64, ld, tid);
  } else if (bid < 6156) {
    int idx = bid - 5132;
    tr64(W1, w1T, 1024, 4096, (idx & 15) * 64, (idx >> 4) * 64, ld, tid);
  } else {
    int idx = bid - 6156;
    tr64(W2, w2T, 4096, 1024, (idx & 63) * 64, (idx >> 6) * 64, ld, tid);
  }
}

// ---------------------------------------------------------------------------
// Fused: V transpose (vt[b,h,dv,t] from qkv col block 2048+h*64) + bf16
// pre-multiplied mask (maskb = bf16(mask * -1e9)). Flat grid 2560.
// ---------------------------------------------------------------------------
__global__ __launch_bounds__(256) void tv_mask(
    const unsigned short* __restrict__ qkv, unsigned short* __restrict__ vt,
    const float* __restrict__ mask, unsigned short* __restrict__ maskb) {
  const int bid = blockIdx.x, tid = threadIdx.x;
  if (bid < 2048) {
    const int t0 = (bid & 15) * 64, h = (bid >> 4) & 15, b = bid >> 8;
    __shared__ unsigned short ld[64][72];
    {
      int r = tid >> 2, c16 = (tid & 3) * 16;
      const unsigned short* s = qkv + (size_t)(b * SS + t0 + r) * 3072 + 2048 + h * 64 + c16;
      *(short8*)(&ld[r][c16]) = *(const short8*)(s);
      *(short8*)(&ld[r][c16 + 8]) = *(const short8*)(s + 8);
    }
    __syncthreads();
    int dv = tid >> 2, t16 = (tid & 3) * 16;
    short8 o0, o1;
#pragma unroll
    for (int i = 0; i < 8; ++i) {
      o0[i] = (short)ld[t16 + i][dv];
      o1[i] = (short)ld[t16 + 8 + i][dv];
    }
    unsigned short* d = vt + ((size_t)(b * HH + h) * DK + dv) * SS + t0 + t16;
    *(short8*)(d) = o0;
    *(short8*)(d + 8) = o1;
  } else {
    int i8 = ((bid - 2048) * 256 + tid) * 8;
    float4 a = *(const float4*)(mask + i8);
    float4 b = *(const float4*)(mask + i8 + 4);
    short8 o;
    o[0] = f2bf(a.x * -1e9f); o[1] = f2bf(a.y * -1e9f);
    o[2] = f2bf(a.z * -1e9f); o[3] = f2bf(a.w * -1e9f);
    o[4] = f2bf(b.x * -1e9f); o[5] = f2bf(b.y * -1e9f);
    o[6] = f2bf(b.z * -1e9f); o[7] = f2bf(b.w * -1e9f);
    *(short8*)(maskb + i8) = o;
  }
}

// ---------------------------------------------------------------------------
// bf16 MFMA GEMM (m97 structure), swapped operands -> b64 epilogue stores.
// ---------------------------------------------------------------------------
template <int RELU>
__global__ __launch_bounds__(256) void gemm_bf16(
    const unsigned short* __restrict__ A, const unsigned short* __restrict__ Bt,
    const float* __restrict__ bias, unsigned short* __restrict__ C,
    int M, int N, int K) {
  const int n0 = blockIdx.x * 128, m0 = blockIdx.y * 128;
  __shared__ __align__(16) unsigned short As[128 * 32];
  __shared__ __align__(16) unsigned short Bs[128 * 32];
  const int tid = threadIdx.x;
  const int wave = tid >> 6, lane = tid & 63;
  const int lm = lane & 15, quad = lane >> 4;
  const int wr = wave >> 1, wc = wave & 1;
  const int srow = lane >> 2;
  const int scol = (lane & 3) * 8;

  floatx4 acc[4][4] = {};

  for (int k0 = 0; k0 < K; k0 += 32) {
#pragma unroll
    for (int j = 0; j < 2; ++j) {
      int rr = wave * 32 + j * 16;
      gload_lds16(A + (size_t)(m0 + rr + srow) * K + k0 + scol, &As[rr * 32]);
      gload_lds16(Bt + (size_t)(n0 + rr + srow) * K + k0 + scol, &Bs[rr * 32]);
    }
    __syncthreads();
    short8 af[4], bf[4];
#pragma unroll
    for (int i = 0; i < 4; ++i)
      af[i] = *(const short8*)&As[(wr * 64 + i * 16 + lm) * 32 + quad * 8];
#pragma unroll
    for (int j = 0; j < 4; ++j)
      bf[j] = *(const short8*)&Bs[(wc * 64 + j * 16 + lm) * 32 + quad * 8];
#pragma unroll
    for (int i = 0; i < 4; ++i)
#pragma unroll
      for (int j = 0; j < 4; ++j)
        acc[i][j] = __builtin_amdgcn_mfma_f32_16x16x32_bf16(bf[j], af[i], acc[i][j], 0, 0, 0);
    __syncthreads();
  }

#pragma unroll
  for (int i = 0; i < 4; ++i) {
    const int row = m0 + wr * 64 + i * 16 + lm;
#pragma unroll
    for (int j = 0; j < 4; ++j) {
      const int c0 = n0 + wc * 64 + j * 16 + quad * 4;
      float4 bv = *(const float4*)(bias + c0);
      float bb[4] = {bv.x, bv.y, bv.z, bv.w};
      short4v o;
#pragma unroll
      for (int r = 0; r < 4; ++r) {
        float v = acc[i][j][r] + bb[r];
        if (RELU) v = fmaxf(v, 0.f);
        o[r] = f2bf(v);
      }
      *(short4v*)(C + (size_t)row * N + c0) = o;
    }
  }
}

// ---------------------------------------------------------------------------
// MFMA attention v3: 512 threads = 8 waves, 16 q-rows/block.
// Pass A: wave w owns t-strip [w*128, w*128+128): 8 iters of 16 t.
// Pass B: wave w handles rows {2w, 2w+1}; bf16 premult mask.
// Pass C: wave w: dv-tile (w&3), t-half (w>>2); LDS partial reduce across
//         t-halves; normalize + b64 store.
// LDS ~38 KB -> 4 blocks/CU; with threads cap 2048/512=4 -> 32 waves/CU.
// ---------------------------------------------------------------------------
__global__ __launch_bounds__(512) void attention_mfma(
    const unsigned short* __restrict__ qkv, const unsigned short* __restrict__ vt,
    const unsigned short* __restrict__ maskb, unsigned short* __restrict__ ctx) {
  const int s0 = blockIdx.x * 16;
  const int h = blockIdx.y, b = blockIdx.z;
  const int tid = threadIdx.x;
  const int wave = tid >> 6, lane = tid & 63;
  const int lm = lane & 15, quad = lane >> 4;

  __shared__ unsigned short P[16 * 1032];      // 33 KB logits/P strip
  __shared__ float wmax[8][16];                // per-wave-strip row max
  __shared__ float rs[16];                     // 1/rowsum
  __shared__ __align__(16) float part[4][64][4];  // 4 KB pass-C partials

  const unsigned short* qp = qkv + (size_t)(b * SS + s0 + lm) * 3072 + h * 64;
  const short8 qa0 = *(const short8*)(qp + quad * 8);
  const short8 qa1 = *(const short8*)(qp + quad * 8 + 32);

  // ---- pass A: logits (swapped: D rows = t, cols = qrow) ----
  float rmax = -3e38f;
  const int tw = wave * 128;
#pragma unroll
  for (int jt = 0; jt < 8; ++jt) {
    const int t0 = tw + jt * 16;
    const unsigned short* kp = qkv + (size_t)(b * SS + t0 + lm) * 3072 + 1024 + h * 64;
    short8 kb0 = *(const short8*)(kp + quad * 8);
    short8 kb1 = *(const short8*)(kp + quad * 8 + 32);
    floatx4 c = {0.f, 0.f, 0.f, 0.f};
    c = __builtin_amdgcn_mfma_f32_16x16x32_bf16(kb0, qa0, c, 0, 0, 0);
    c = __builtin_amdgcn_mfma_f32_16x16x32_bf16(kb1, qa1, c, 0, 0, 0);
    short4v o;
#pragma unroll
    for (int r = 0; r < 4; ++r) {
      float sv = c[r] * 0.125f;     // logit for (qrow=lm, t=t0+quad*4+r)
      rmax = fmaxf(rmax, sv);
      o[r] = f2bf(sv);
    }
    *(short4v*)(P + lm * 1032 + t0 + quad * 4) = o;
  }
  rmax = fmaxf(rmax, __shfl_xor(rmax, 16));
  rmax = fmaxf(rmax, __shfl_xor(rmax, 32));
  if (lane < 16) wmax[wave][lm] = rmax;
  __syncthreads();

  // ---- pass B: mask + exp + sum (rows 2w, 2w+1) ----
#pragma unroll
  for (int ri = 0; ri < 2; ++ri) {
    const int row = wave * 2 + ri;
    float gmax = wmax[0][row];
#pragma unroll
    for (int wv = 1; wv < 8; ++wv) gmax = fmaxf(gmax, wmax[wv][row]);
    unsigned short* prow = P + row * 1032 + lane * 16;
    const unsigned short* mrow = maskb + (size_t)(s0 + row) * SS + lane * 16;
    short8 x0 = *(short8*)(prow);
    short8 x1 = *(short8*)(prow + 8);
    short8 m0 = *(const short8*)(mrow);
    short8 m1 = *(const short8*)(mrow + 8);
    float sm = 0.f;
#pragma unroll
    for (int i = 0; i < 8; ++i) {
      float f0 = __expf(bf2f((unsigned short)x0[i]) + bf2f((unsigned short)m0[i]) - gmax);
      float f1 = __expf(bf2f((unsigned short)x1[i]) + bf2f((unsigned short)m1[i]) - gmax);
      sm += f0 + f1;
      x0[i] = f2bf(f0);
      x1[i] = f2bf(f1);
    }
#pragma unroll
    for (int o = 1; o < 64; o <<= 1) sm += __shfl_xor(sm, o);
    *(short8*)(prow) = x0;
    *(short8*)(prow + 8) = x1;
    if (lane == 0) rs[row] = 1.f / sm;
  }
  __syncthreads();

  // ---- pass C: ctx^T = V^T @ P^T; wave: dv-tile (w&3), t-half (w>>2) ----
  const int dv0 = (wave & 3) * 16;
  const int th = wave >> 2;
  const size_t vbase = (size_t)(b * HH + h) * DK * SS;
  const unsigned short* vrow = vt + vbase + (size_t)(dv0 + lm) * SS;
  floatx4 acc = {0.f, 0.f, 0.f, 0.f};
#pragma unroll
  for (int jt = 0; jt < 8; ++jt) {
    const int t0 = th * 512 + jt * 64;
    short8 va0 = *(const short8*)(vrow + t0 + quad * 8);
    short8 pb0 = *(const short8*)(P + lm * 1032 + t0 + quad * 8);
    acc = __builtin_amdgcn_mfma_f32_16x16x32_bf16(va0, pb0, acc, 0, 0, 0);
    short8 va1 = *(const short8*)(vrow + t0 + 32 + quad * 8);
    short8 pb1 = *(const short8*)(P + lm * 1032 + t0 + 32 + quad * 8);
    acc = __builtin_amdgcn_mfma_f32_16x16x32_bf16(va1, pb1, acc, 0, 0, 0);
  }
  if (th == 1) *(floatx4*)(&part[wave & 3][lane][0]) = acc;
  __syncthreads();
  if (th == 0) {
    floatx4 p2 = *(const floatx4*)(&part[wave][lane][0]);
    const float sc = rs[lm];
    short4v o;
#pragma unroll
    for (int r = 0; r < 4; ++r) o[r] = f2bf((acc[r] + p2[r]) * sc);
    // lane holds D[dv=dv0+quad*4+r][qrow=lm]
    *(short4v*)(ctx + (size_t)(b * SS + s0 + lm) * DD + h * DK + dv0 + quad * 4) = o;
  }
}

// ---------------------------------------------------------------------------
// Residual + LayerNorm: out = LN(a + r) * w + b. One block per row (D=1024).
// ---------------------------------------------------------------------------
template <int A_BF16, int OUT_BF16>
__global__ __launch_bounds__(256) void residual_ln(
    const void* __restrict__ a_, const unsigned short* __restrict__ rr,
    const float* __restrict__ w, const float* __restrict__ bias,
    void* __restrict__ out_) {
  const int row = blockIdx.x;
  const int t = threadIdx.x;
  float x[4];
  if (A_BF16) {
    short4v va = *(const short4v*)((const unsigned short*)a_ + (size_t)row * DD + t * 4);
#pragma unroll
    for (int i = 0; i < 4; ++i) x[i] = bf2f((unsigned short)va[i]);
  } else {
    float4 va = *(const float4*)((const float*)a_ + (size_t)row * DD + t * 4);
    x[0] = va.x; x[1] = va.y; x[2] = va.z; x[3] = va.w;
  }
  {
    short4v vr = *(const short4v*)(rr + (size_t)row * DD + t * 4);
#pragma unroll
    for (int i = 0; i < 4; ++i) x[i] += bf2f((unsigned short)vr[i]);
  }
  float s = 0.f, ss = 0.f;
#pragma unroll
  for (int i = 0; i < 4; ++i) { s += x[i]; ss += x[i] * x[i]; }
#pragma unroll
  for (int o = 32; o > 0; o >>= 1) {
    s  += __shfl_down(s, o);
    ss += __shfl_down(ss, o);
  }
  __shared__ float2 sred[4];
  int wid = t >> 6;
  if ((t & 63) == 0) sred[wid] = make_float2(s, ss);
  __syncthreads();
  float st = 0.f, sst = 0.f;
#pragma unroll
  for (int i = 0; i < 4; ++i) { st += sred[i].x; sst += sred[i].y; }
  float mu  = st * (1.f / 1024.f);
  float var = sst * (1.f / 1024.f) - mu * mu;
  float rsq = rsqrtf(var + 1e-5f);
  float4 vw = *(const float4*)(w + t * 4);
  float4 vb = *(const float4*)(bias + t * 4);
  float o[4];
  o[0] = (x[0] - mu) * rsq * vw.x + vb.x;
  o[1] = (x[1] - mu) * rsq * vw.y + vb.y;
  o[2] = (x[2] - mu) * rsq * vw.z + vb.z;
  o[3] = (x[3] - mu) * rsq * vw.w + vb.w;
  if (OUT_BF16) {
    short4v ov;
#pragma unroll
    for (int i = 0; i < 4; ++i) ov[i] = f2bf(o[i]);
    *(short4v*)((unsigned short*)out_ + (size_t)row * DD + t * 4) = ov;
  } else {
    float4 ov = {o[0], o[1], o[2], o[3]};
    *(float4*)((float*)out_ + (size_t)row * DD + t * 4) = ov;
  }
}

// ---------------------------------------------------------------------------
extern "C" void kernel_launch(void* const* d_in, const int* in_sizes, int n_in,
                              void* d_out, int out_size, void* d_ws, size_t ws_size,
                              hipStream_t stream) {
  const float* src  = (const float*)d_in[0];
  const float* mask = (const float*)d_in[1];
  const float* Wq = (const float*)d_in[2];  const float* bq = (const float*)d_in[3];
  const float* Wk = (const float*)d_in[4];  const float* bk = (const float*)d_in[5];
  const float* Wv = (const float*)d_in[6];  const float* bv = (const float*)d_in[7];
  const float* Wo = (const float*)d_in[8];  const float* bo = (const float*)d_in[9];
  const float* ln1w = (const float*)d_in[10]; const float* ln1b = (const float*)d_in[11];
  const float* W1 = (const float*)d_in[12]; const float* b1 = (const float*)d_in[13];
  const float* W2 = (const float*)d_in[14]; const float* b2 = (const float*)d_in[15];
  const float* ln2w = (const float*)d_in[16]; const float* ln2b = (const float*)d_in[17];
  float* out = (float*)d_out;

  // Workspace layout (byte offsets), total 125,841,408 B (~120 MiB):
  //  [  0, 48M)  qkv bf16 [M,3072]          -> h1 bf16 [M,4096] (after LN1)
  //  [ 48, 64M)  vt bf16 [B,H,DK,S]         -> attn_out bf16 (after attention)
  //  [ 64, 80M)  ctx bf16 [M,1024]          -> xb bf16 (after Wo gemm)
  //  [ 80, 96M)  srcb bf16 [M,1024] (dead after QKV gemm) -> maskb bf16 [S,S]
  //              (alive through attention) -> ffn bf16 (written by W2 gemm)
  //  [ 96,120M)  weights: wqkvT, woT, w1T, w2T, bqkv
  const size_t NEED = 125841408;
  if (ws_size < NEED) return;

  char* ws = (char*)d_ws;
  unsigned short* qkv   = (unsigned short*)(ws);
  unsigned short* vtb   = (unsigned short*)(ws + 50331648);
  unsigned short* ctxb  = (unsigned short*)(ws + 67108864);
  unsigned short* srcb  = (unsigned short*)(ws + 83886080);
  unsigned short* wqkvT = (unsigned short*)(ws + 100663296);  // [3072,1024]
  unsigned short* woT   = (unsigned short*)(ws + 106954752);  // [1024,1024]
  unsigned short* w1T   = (unsigned short*)(ws + 109051904);  // [4096,1024]
  unsigned short* w2T   = (unsigned short*)(ws + 117440512);  // [1024,4096]
  float*          bqkv  = (float*)(ws + 125829120);           // [3072]
  unsigned short* maskb    = srcb;  // [S,S] bf16 premult; srcb dead after QKV gemm
  unsigned short* h1       = qkv;   // [M,4096] spans qkv+vtb
  unsigned short* attn_out = vtb;
  unsigned short* xb       = ctxb;
  unsigned short* ffn      = srcb;  // written after maskb's last read

  prep_all<<<7180, 256, 0, stream>>>(src, Wq, Wk, Wv, bq, bk, bv, Wo, W1, W2,
                                     srcb, wqkvT, bqkv, woT, w1T, w2T);
  gemm_bf16<0><<<dim3(3072 / 128, MM / 128), 256, 0, stream>>>(srcb, wqkvT, bqkv, qkv, MM, 3072, DD);
  tv_mask<<<2560, 256, 0, stream>>>(qkv, vtb, mask, maskb);
  attention_mfma<<<dim3(SS / 16, HH, BB), 512, 0, stream>>>(qkv, vtb, maskb, ctxb);
  gemm_bf16<0><<<dim3(DD / 128, MM / 128), 256, 0, stream>>>(ctxb, woT, bo, attn_out, MM, DD, DD);
  residual_ln<0, 1><<<MM, 256, 0, stream>>>(src, attn_out, ln1w, ln1b, xb);
  gemm_bf16<1><<<dim3(FF / 128, MM / 128), 256, 0, stream>>>(xb, w1T, b1, h1, MM, FF, DD);
  gemm_bf16<0><<<dim3(DD / 128, MM / 128), 256, 0, stream>>>(h1, w2T, b2, ffn, MM, DD, FF);
  residual_ln<1, 0><<<MM, 256, 0, stream>>>(xb, ffn, ln2w, ln2b, out);
}

// Round 7
// 782.952 us; speedup vs baseline: 1.0292x; 1.0010x over previous
//
#include <hip/hip_runtime.h>

// Shapes (fixed by the reference)
#define BB 8
#define SS 1024
#define DD 1024
#define HH 16
#define DK 64
#define FF 4096
#define MM (BB*SS)   // 8192

typedef __attribute__((ext_vector_type(8))) short short8;
typedef __attribute__((ext_vector_type(4))) short short4v;
typedef __attribute__((ext_vector_type(4))) float floatx4;

__device__ inline short f2bf(float f) {
  union { float f; unsigned u; } v; v.f = f;
  unsigned r = (v.u + 0x7FFFu + ((v.u >> 16) & 1u)) >> 16;
  return (short)r;
}
__device__ inline float bf2f(unsigned short u) {
  union { unsigned u; float f; } v; v.u = ((unsigned)u) << 16;
  return v.f;
}

// async global->LDS, 16B per lane; lds dst must be wave-uniform base (+lane*16)
__device__ inline void gload_lds16(const void* g, void* l) {
  __builtin_amdgcn_global_load_lds(
      (const __attribute__((address_space(1))) void*)g,
      (__attribute__((address_space(3))) void*)l, 16, 0, 0);
}

// ---------------------------------------------------------------------------
// Fused prep kernel (flat grid, 256 thr):
//  [0,4096)      cvt src fp32 -> bf16 (srcb)
//  [4096,4864)   WqkvT [3072,1024]: WqkvT[z*1024+h*64+dk][d] = Wz[h][d][dk]
//  [4864,4876)   bqkv concat
//  [4876,5132)   WoT  [1024,1024]
//  [5132,6156)   W1T  [4096,1024]
//  [6156,7180)   W2T  [1024,4096]
// ---------------------------------------------------------------------------
__device__ void tr64(const float* __restrict__ s, unsigned short* __restrict__ d,
                     int R, int C, int r0, int c0, float (*ld)[68], int tid) {
  {
    int r = tid >> 2, c16 = (tid & 3) * 16;
#pragma unroll
    for (int i = 0; i < 4; ++i)
      *(float4*)(&ld[r][c16 + i * 4]) =
          *(const float4*)(s + (size_t)(r0 + r) * C + c0 + c16 + i * 4);
  }
  __syncthreads();
  int c = tid >> 2, r16 = (tid & 3) * 16;
  short8 o0, o1;
#pragma unroll
  for (int i = 0; i < 8; ++i) {
    o0[i] = f2bf(ld[r16 + i][c]);
    o1[i] = f2bf(ld[r16 + 8 + i][c]);
  }
  unsigned short* dp = d + (size_t)(c0 + c) * R + r0 + r16;
  *(short8*)(dp) = o0;
  *(short8*)(dp + 8) = o1;
}

__global__ __launch_bounds__(256) void prep_all(
    const float* __restrict__ src,
    const float* __restrict__ Wq, const float* __restrict__ Wk,
    const float* __restrict__ Wv,
    const float* __restrict__ bq, const float* __restrict__ bk,
    const float* __restrict__ bv,
    const float* __restrict__ Wo, const float* __restrict__ W1,
    const float* __restrict__ W2,
    unsigned short* __restrict__ srcb, unsigned short* __restrict__ wqkvT,
    float* __restrict__ bqkv, unsigned short* __restrict__ woT,
    unsigned short* __restrict__ w1T, unsigned short* __restrict__ w2T) {
  __shared__ float ld[64][68];
  const int bid = blockIdx.x, tid = threadIdx.x;
  if (bid < 4096) {
    int i8 = (bid * 256 + tid) * 8;
    float4 a = *(const float4*)(src + i8);
    float4 b = *(const float4*)(src + i8 + 4);
    short8 o;
    o[0] = f2bf(a.x); o[1] = f2bf(a.y); o[2] = f2bf(a.z); o[3] = f2bf(a.w);
    o[4] = f2bf(b.x); o[5] = f2bf(b.y); o[6] = f2bf(b.z); o[7] = f2bf(b.w);
    *(short8*)(srcb + i8) = o;
  } else if (bid < 4864) {
    int idx = bid - 4096;
    int d0 = (idx & 15) * 64, h = (idx >> 4) & 15, z = idx >> 8;
    const float* W = (z == 0 ? Wq : z == 1 ? Wk : Wv) + (size_t)h * DD * DK;
    {
      int r = tid >> 2, c16 = (tid & 3) * 16;
#pragma unroll
      for (int i = 0; i < 4; ++i)
        *(float4*)(&ld[r][c16 + i * 4]) =
            *(const float4*)(W + (size_t)(d0 + r) * DK + c16 + i * 4);
    }
    __syncthreads();
    int dv = tid >> 2, d16 = (tid & 3) * 16;
    short8 o0, o1;
#pragma unroll
    for (int i = 0; i < 8; ++i) {
      o0[i] = f2bf(ld[d16 + i][dv]);
      o1[i] = f2bf(ld[d16 + 8 + i][dv]);
    }
    unsigned short* dst = wqkvT + (size_t)(z * 1024 + h * 64 + dv) * DD + d0 + d16;
    *(short8*)(dst) = o0;
    *(short8*)(dst + 8) = o1;
  } else if (bid < 4876) {
    int n = (bid - 4864) * 256 + tid;   // 0..3071
    int z = n >> 10;
    const float* s = (z == 0 ? bq : z == 1 ? bk : bv);
    bqkv[n] = s[n & 1023];
  } else if (bid < 5132) {
    int idx = bid - 4876;
    tr64(Wo, woT, 1024, 1024, (idx & 15) * 64, (idx >> 4) * 64, ld, tid);
  } else if (bid < 6156) {
    int idx = bid - 5132;
    tr64(W1, w1T, 1024, 4096, (idx & 15) * 64, (idx >> 4) * 64, ld, tid);
  } else {
    int idx = bid - 6156;
    tr64(W2, w2T, 4096, 1024, (idx & 63) * 64, (idx >> 6) * 64, ld, tid);
  }
}

// ---------------------------------------------------------------------------
// Fused: V transpose (vt[b,h,dv,t] from qkv col block 2048+h*64) + bf16
// pre-multiplied mask (maskb = bf16(mask * -1e9)). Flat grid 2560.
// ---------------------------------------------------------------------------
__global__ __launch_bounds__(256) void tv_mask(
    const unsigned short* __restrict__ qkv, unsigned short* __restrict__ vt,
    const float* __restrict__ mask, unsigned short* __restrict__ maskb) {
  const int bid = blockIdx.x, tid = threadIdx.x;
  if (bid < 2048) {
    const int t0 = (bid & 15) * 64, h = (bid >> 4) & 15, b = bid >> 8;
    __shared__ unsigned short ld[64][72];
    {
      int r = tid >> 2, c16 = (tid & 3) * 16;
      const unsigned short* s = qkv + (size_t)(b * SS + t0 + r) * 3072 + 2048 + h * 64 + c16;
      *(short8*)(&ld[r][c16]) = *(const short8*)(s);
      *(short8*)(&ld[r][c16 + 8]) = *(const short8*)(s + 8);
    }
    __syncthreads();
    int dv = tid >> 2, t16 = (tid & 3) * 16;
    short8 o0, o1;
#pragma unroll
    for (int i = 0; i < 8; ++i) {
      o0[i] = (short)ld[t16 + i][dv];
      o1[i] = (short)ld[t16 + 8 + i][dv];
    }
    unsigned short* d = vt + ((size_t)(b * HH + h) * DK + dv) * SS + t0 + t16;
    *(short8*)(d) = o0;
    *(short8*)(d + 8) = o1;
  } else {
    int i8 = ((bid - 2048) * 256 + tid) * 8;
    float4 a = *(const float4*)(mask + i8);
    float4 b = *(const float4*)(mask + i8 + 4);
    short8 o;
    o[0] = f2bf(a.x * -1e9f); o[1] = f2bf(a.y * -1e9f);
    o[2] = f2bf(a.z * -1e9f); o[3] = f2bf(a.w * -1e9f);
    o[4] = f2bf(b.x * -1e9f); o[5] = f2bf(b.y * -1e9f);
    o[6] = f2bf(b.z * -1e9f); o[7] = f2bf(b.w * -1e9f);
    *(short8*)(maskb + i8) = o;
  }
}

// ---------------------------------------------------------------------------
// bf16 MFMA GEMM (m97 structure), swapped operands -> b64 epilogue stores.
// ---------------------------------------------------------------------------
template <int RELU>
__global__ __launch_bounds__(256) void gemm_bf16(
    const unsigned short* __restrict__ A, const unsigned short* __restrict__ Bt,
    const float* __restrict__ bias, unsigned short* __restrict__ C,
    int M, int N, int K) {
  const int n0 = blockIdx.x * 128, m0 = blockIdx.y * 128;
  __shared__ __align__(16) unsigned short As[128 * 32];
  __shared__ __align__(16) unsigned short Bs[128 * 32];
  const int tid = threadIdx.x;
  const int wave = tid >> 6, lane = tid & 63;
  const int lm = lane & 15, quad = lane >> 4;
  const int wr = wave >> 1, wc = wave & 1;
  const int srow = lane >> 2;
  const int scol = (lane & 3) * 8;

  floatx4 acc[4][4] = {};

  for (int k0 = 0; k0 < K; k0 += 32) {
#pragma unroll
    for (int j = 0; j < 2; ++j) {
      int rr = wave * 32 + j * 16;
      gload_lds16(A + (size_t)(m0 + rr + srow) * K + k0 + scol, &As[rr * 32]);
      gload_lds16(Bt + (size_t)(n0 + rr + srow) * K + k0 + scol, &Bs[rr * 32]);
    }
    __syncthreads();
    short8 af[4], bf[4];
#pragma unroll
    for (int i = 0; i < 4; ++i)
      af[i] = *(const short8*)&As[(wr * 64 + i * 16 + lm) * 32 + quad * 8];
#pragma unroll
    for (int j = 0; j < 4; ++j)
      bf[j] = *(const short8*)&Bs[(wc * 64 + j * 16 + lm) * 32 + quad * 8];
#pragma unroll
    for (int i = 0; i < 4; ++i)
#pragma unroll
      for (int j = 0; j < 4; ++j)
        acc[i][j] = __builtin_amdgcn_mfma_f32_16x16x32_bf16(bf[j], af[i], acc[i][j], 0, 0, 0);
    __syncthreads();
  }

#pragma unroll
  for (int i = 0; i < 4; ++i) {
    const int row = m0 + wr * 64 + i * 16 + lm;
#pragma unroll
    for (int j = 0; j < 4; ++j) {
      const int c0 = n0 + wc * 64 + j * 16 + quad * 4;
      float4 bv = *(const float4*)(bias + c0);
      float bb[4] = {bv.x, bv.y, bv.z, bv.w};
      short4v o;
#pragma unroll
      for (int r = 0; r < 4; ++r) {
        float v = acc[i][j][r] + bb[r];
        if (RELU) v = fmaxf(v, 0.f);
        o[r] = f2bf(v);
      }
      *(short4v*)(C + (size_t)row * N + c0) = o;
    }
  }
}

// ---------------------------------------------------------------------------
// MFMA attention v4: 512 threads = 8 waves, 16 q-rows/block.
// Changes vs v3:
//  * __launch_bounds__(512,4): VGPR cap 128 (was 32) -> room for prefetch regs.
//  * Pass A/C: explicit 4-deep register prefetch rotation (8 loads in flight
//    per wave instead of ~1 -> latency-chain broken).
//  * Flat-grid XCD swizzle: all 64 s0-blocks of one (b,h) land on the SAME
//    XCD, time-adjacent (round-robin block->XCD) -> K/V stay in that XCD's L2.
// ---------------------------------------------------------------------------
__global__ __launch_bounds__(512, 4) void attention_mfma(
    const unsigned short* __restrict__ qkv, const unsigned short* __restrict__ vt,
    const unsigned short* __restrict__ maskb, unsigned short* __restrict__ ctx) {
  // flat = xcd + 8*(s0i + 64*bh_hi); bh = xcd + 8*bh_hi
  const int flat = blockIdx.x;
  const int bh = (flat & 7) + 8 * (flat >> 9);
  const int s0i = (flat >> 3) & 63;
  const int b = bh >> 4, h = bh & 15;
  const int s0 = s0i * 16;
  const int tid = threadIdx.x;
  const int wave = tid >> 6, lane = tid & 63;
  const int lm = lane & 15, quad = lane >> 4;

  __shared__ unsigned short P[16 * 1032];      // 33 KB logits/P strip
  __shared__ float wmax[8][16];                // per-wave-strip row max
  __shared__ float rs[16];                     // 1/rowsum
  __shared__ __align__(16) float part[4][64][4];  // 4 KB pass-C partials

  const unsigned short* qp = qkv + (size_t)(b * SS + s0 + lm) * 3072 + h * 64;
  const short8 qa0 = *(const short8*)(qp + quad * 8);
  const short8 qa1 = *(const short8*)(qp + quad * 8 + 32);

  // ---- pass A: logits, 4-deep K prefetch ----
  const int tw = wave * 128;
  const unsigned short* kbase =
      qkv + (size_t)(b * SS + tw + lm) * 3072 + 1024 + h * 64 + quad * 8;
  short8 kb[4][2];
#pragma unroll
  for (int p = 0; p < 4; ++p) {
    kb[p][0] = *(const short8*)(kbase + p * 49152);         // 16 rows * 3072
    kb[p][1] = *(const short8*)(kbase + p * 49152 + 32);
  }
  float rmax = -3e38f;
#pragma unroll
  for (int jt = 0; jt < 8; ++jt) {
    floatx4 c = {0.f, 0.f, 0.f, 0.f};
    c = __builtin_amdgcn_mfma_f32_16x16x32_bf16(kb[jt & 3][0], qa0, c, 0, 0, 0);
    c = __builtin_amdgcn_mfma_f32_16x16x32_bf16(kb[jt & 3][1], qa1, c, 0, 0, 0);
    if (jt < 4) {
      kb[jt & 3][0] = *(const short8*)(kbase + (jt + 4) * 49152);
      kb[jt & 3][1] = *(const short8*)(kbase + (jt + 4) * 49152 + 32);
    }
    short4v o;
#pragma unroll
    for (int r = 0; r < 4; ++r) {
      float sv = c[r] * 0.125f;     // logit for (qrow=lm, t=tw+jt*16+quad*4+r)
      rmax = fmaxf(rmax, sv);
      o[r] = f2bf(sv);
    }
    *(short4v*)(P + lm * 1032 + tw + jt * 16 + quad * 4) = o;
  }
  rmax = fmaxf(rmax, __shfl_xor(rmax, 16));
  rmax = fmaxf(rmax, __shfl_xor(rmax, 32));
  if (lane < 16) wmax[wave][lm] = rmax;
  __syncthreads();

  // ---- pass B: mask + exp + sum (rows 2w, 2w+1) ----
#pragma unroll
  for (int ri = 0; ri < 2; ++ri) {
    const int row = wave * 2 + ri;
    float gmax = wmax[0][row];
#pragma unroll
    for (int wv = 1; wv < 8; ++wv) gmax = fmaxf(gmax, wmax[wv][row]);
    unsigned short* prow = P + row * 1032 + lane * 16;
    const unsigned short* mrow = maskb + (size_t)(s0 + row) * SS + lane * 16;
    short8 m0 = *(const short8*)(mrow);
    short8 m1 = *(const short8*)(mrow + 8);
    short8 x0 = *(short8*)(prow);
    short8 x1 = *(short8*)(prow + 8);
    float sm = 0.f;
#pragma unroll
    for (int i = 0; i < 8; ++i) {
      float f0 = __expf(bf2f((unsigned short)x0[i]) + bf2f((unsigned short)m0[i]) - gmax);
      float f1 = __expf(bf2f((unsigned short)x1[i]) + bf2f((unsigned short)m1[i]) - gmax);
      sm += f0 + f1;
      x0[i] = f2bf(f0);
      x1[i] = f2bf(f1);
    }
#pragma unroll
    for (int o = 1; o < 64; o <<= 1) sm += __shfl_xor(sm, o);
    *(short8*)(prow) = x0;
    *(short8*)(prow + 8) = x1;
    if (lane == 0) rs[row] = 1.f / sm;
  }
  __syncthreads();

  // ---- pass C: ctx^T = V^T @ P^T; wave: dv-tile (w&3), t-half (w>>2);
  //      4-deep V prefetch ----
  const int dv0 = (wave & 3) * 16;
  const int th = wave >> 2;
  const unsigned short* vbase2 = vt + ((size_t)(b * HH + h) * DK + dv0 + lm) * SS
                                 + th * 512 + quad * 8;
  const unsigned short* pbase = P + lm * 1032 + th * 512 + quad * 8;
  short8 va[4][2];
#pragma unroll
  for (int p = 0; p < 4; ++p) {
    va[p][0] = *(const short8*)(vbase2 + p * 64);
    va[p][1] = *(const short8*)(vbase2 + p * 64 + 32);
  }
  floatx4 acc = {0.f, 0.f, 0.f, 0.f};
#pragma unroll
  for (int jt = 0; jt < 8; ++jt) {
    short8 pb0 = *(const short8*)(pbase + jt * 64);
    short8 pb1 = *(const short8*)(pbase + jt * 64 + 32);
    acc = __builtin_amdgcn_mfma_f32_16x16x32_bf16(va[jt & 3][0], pb0, acc, 0, 0, 0);
    acc = __builtin_amdgcn_mfma_f32_16x16x32_bf16(va[jt & 3][1], pb1, acc, 0, 0, 0);
    if (jt < 4) {
      va[jt & 3][0] = *(const short8*)(vbase2 + (jt + 4) * 64);
      va[jt & 3][1] = *(const short8*)(vbase2 + (jt + 4) * 64 + 32);
    }
  }
  if (th == 1) *(floatx4*)(&part[wave & 3][lane][0]) = acc;
  __syncthreads();
  if (th == 0) {
    floatx4 p2 = *(const floatx4*)(&part[wave][lane][0]);
    const float sc = rs[lm];
    short4v o;
#pragma unroll
    for (int r = 0; r < 4; ++r) o[r] = f2bf((acc[r] + p2[r]) * sc);
    // lane holds D[dv=dv0+quad*4+r][qrow=lm]
    *(short4v*)(ctx + (size_t)(b * SS + s0 + lm) * DD + h * DK + dv0 + quad * 4) = o;
  }
}

// ---------------------------------------------------------------------------
// Residual + LayerNorm: out = LN(a + r) * w + b. One block per row (D=1024).
// ---------------------------------------------------------------------------
template <int A_BF16, int OUT_BF16>
__global__ __launch_bounds__(256) void residual_ln(
    const void* __restrict__ a_, const unsigned short* __restrict__ rr,
    const float* __restrict__ w, const float* __restrict__ bias,
    void* __restrict__ out_) {
  const int row = blockIdx.x;
  const int t = threadIdx.x;
  float x[4];
  if (A_BF16) {
    short4v va = *(const short4v*)((const unsigned short*)a_ + (size_t)row * DD + t * 4);
#pragma unroll
    for (int i = 0; i < 4; ++i) x[i] = bf2f((unsigned short)va[i]);
  } else {
    float4 va = *(const float4*)((const float*)a_ + (size_t)row * DD + t * 4);
    x[0] = va.x; x[1] = va.y; x[2] = va.z; x[3] = va.w;
  }
  {
    short4v vr = *(const short4v*)(rr + (size_t)row * DD + t * 4);
#pragma unroll
    for (int i = 0; i < 4; ++i) x[i] += bf2f((unsigned short)vr[i]);
  }
  float s = 0.f, ss = 0.f;
#pragma unroll
  for (int i = 0; i < 4; ++i) { s += x[i]; ss += x[i] * x[i]; }
#pragma unroll
  for (int o = 32; o > 0; o >>= 1) {
    s  += __shfl_down(s, o);
    ss += __shfl_down(ss, o);
  }
  __shared__ float2 sred[4];
  int wid = t >> 6;
  if ((t & 63) == 0) sred[wid] = make_float2(s, ss);
  __syncthreads();
  float st = 0.f, sst = 0.f;
#pragma unroll
  for (int i = 0; i < 4; ++i) { st += sred[i].x; sst += sred[i].y; }
  float mu  = st * (1.f / 1024.f);
  float var = sst * (1.f / 1024.f) - mu * mu;
  float rsq = rsqrtf(var + 1e-5f);
  float4 vw = *(const float4*)(w + t * 4);
  float4 vb = *(const float4*)(bias + t * 4);
  float o[4];
  o[0] = (x[0] - mu) * rsq * vw.x + vb.x;
  o[1] = (x[1] - mu) * rsq * vw.y + vb.y;
  o[2] = (x[2] - mu) * rsq * vw.z + vb.z;
  o[3] = (x[3] - mu) * rsq * vw.w + vb.w;
  if (OUT_BF16) {
    short4v ov;
#pragma unroll
    for (int i = 0; i < 4; ++i) ov[i] = f2bf(o[i]);
    *(short4v*)((unsigned short*)out_ + (size_t)row * DD + t * 4) = ov;
  } else {
    float4 ov = {o[0], o[1], o[2], o[3]};
    *(float4*)((float*)out_ + (size_t)row * DD + t * 4) = ov;
  }
}

// ---------------------------------------------------------------------------
extern "C" void kernel_launch(void* const* d_in, const int* in_sizes, int n_in,
                              void* d_out, int out_size, void* d_ws, size_t ws_size,
                              hipStream_t stream) {
  const float* src  = (const float*)d_in[0];
  const float* mask = (const float*)d_in[1];
  const float* Wq = (const float*)d_in[2];  const float* bq = (const float*)d_in[3];
  const float* Wk = (const float*)d_in[4];  const float* bk = (const float*)d_in[5];
  const float* Wv = (const float*)d_in[6];  const float* bv = (const float*)d_in[7];
  const float* Wo = (const float*)d_in[8];  const float* bo = (const float*)d_in[9];
  const float* ln1w = (const float*)d_in[10]; const float* ln1b = (const float*)d_in[11];
  const float* W1 = (const float*)d_in[12]; const float* b1 = (const float*)d_in[13];
  const float* W2 = (const float*)d_in[14]; const float* b2 = (const float*)d_in[15];
  const float* ln2w = (const float*)d_in[16]; const float* ln2b = (const float*)d_in[17];
  float* out = (float*)d_out;

  // Workspace layout (byte offsets), total 125,841,408 B (~120 MiB):
  //  [  0, 48M)  qkv bf16 [M,3072]          -> h1 bf16 [M,4096] (after LN1)
  //  [ 48, 64M)  vt bf16 [B,H,DK,S]         -> attn_out bf16 (after attention)
  //  [ 64, 80M)  ctx bf16 [M,1024]          -> xb bf16 (after Wo gemm)
  //  [ 80, 96M)  srcb bf16 [M,1024] (dead after QKV gemm) -> maskb bf16 [S,S]
  //              (alive through attention) -> ffn bf16 (written by W2 gemm)
  //  [ 96,120M)  weights: wqkvT, woT, w1T, w2T, bqkv
  const size_t NEED = 125841408;
  if (ws_size < NEED) return;

  char* ws = (char*)d_ws;
  unsigned short* qkv   = (unsigned short*)(ws);
  unsigned short* vtb   = (unsigned short*)(ws + 50331648);
  unsigned short* ctxb  = (unsigned short*)(ws + 67108864);
  unsigned short* srcb  = (unsigned short*)(ws + 83886080);
  unsigned short* wqkvT = (unsigned short*)(ws + 100663296);  // [3072,1024]
  unsigned short* woT   = (unsigned short*)(ws + 106954752);  // [1024,1024]
  unsigned short* w1T   = (unsigned short*)(ws + 109051904);  // [4096,1024]
  unsigned short* w2T   = (unsigned short*)(ws + 117440512);  // [1024,4096]
  float*          bqkv  = (float*)(ws + 125829120);           // [3072]
  unsigned short* maskb    = srcb;  // [S,S] bf16 premult; srcb dead after QKV gemm
  unsigned short* h1       = qkv;   // [M,4096] spans qkv+vtb
  unsigned short* attn_out = vtb;
  unsigned short* xb       = ctxb;
  unsigned short* ffn      = srcb;  // written after maskb's last read

  prep_all<<<7180, 256, 0, stream>>>(src, Wq, Wk, Wv, bq, bk, bv, Wo, W1, W2,
                                     srcb, wqkvT, bqkv, woT, w1T, w2T);
  gemm_bf16<0><<<dim3(3072 / 128, MM / 128), 256, 0, stream>>>(srcb, wqkvT, bqkv, qkv, MM, 3072, DD);
  tv_mask<<<2560, 256, 0, stream>>>(qkv, vtb, mask, maskb);
  attention_mfma<<<8192, 512, 0, stream>>>(qkv, vtb, maskb, ctxb);
  gemm_bf16<0><<<dim3(DD / 128, MM / 128), 256, 0, stream>>>(ctxb, woT, bo, attn_out, MM, DD, DD);
  residual_ln<0, 1><<<MM, 256, 0, stream>>>(src, attn_out, ln1w, ln1b, xb);
  gemm_bf16<1><<<dim3(FF / 128, MM / 128), 256, 0, stream>>>(xb, w1T, b1, h1, MM, FF, DD);
  gemm_bf16<0><<<dim3(DD / 128, MM / 128), 256, 0, stream>>>(h1, w2T, b2, ffn, MM, DD, FF);
  residual_ln<1, 0><<<MM, 256, 0, stream>>>(xb, ffn, ln2w, ln2b, out);
}

// Round 8
// 614.450 us; speedup vs baseline: 1.3114x; 1.2742x over previous
//
#include <hip/hip_runtime.h>

// Shapes (fixed by the reference)
#define BB 8
#define SS 1024
#define DD 1024
#define HH 16
#define DK 64
#define FF 4096
#define MM (BB*SS)   // 8192

typedef __attribute__((ext_vector_type(8))) short short8;
typedef __attribute__((ext_vector_type(4))) short short4v;
typedef __attribute__((ext_vector_type(4))) float floatx4;

__device__ inline short f2bf(float f) {
  union { float f; unsigned u; } v; v.f = f;
  unsigned r = (v.u + 0x7FFFu + ((v.u >> 16) & 1u)) >> 16;
  return (short)r;
}
__device__ inline float bf2f(unsigned short u) {
  union { unsigned u; float f; } v; v.u = ((unsigned)u) << 16;
  return v.f;
}

// async global->LDS, 16B per lane; lds dst = wave-uniform base + lane*16
__device__ inline void gload_lds16(const void* g, void* l) {
  __builtin_amdgcn_global_load_lds(
      (const __attribute__((address_space(1))) void*)g,
      (__attribute__((address_space(3))) void*)l, 16, 0, 0);
}

// ---------------------------------------------------------------------------
// tr64: transpose one 64x64 tile fp32 [R][C] -> bf16 [C][R]
// ---------------------------------------------------------------------------
__device__ void tr64(const float* __restrict__ s, unsigned short* __restrict__ d,
                     int R, int C, int r0, int c0, float (*ld)[68], int tid) {
  {
    int r = tid >> 2, c16 = (tid & 3) * 16;
#pragma unroll
    for (int i = 0; i < 4; ++i)
      *(float4*)(&ld[r][c16 + i * 4]) =
          *(const float4*)(s + (size_t)(r0 + r) * C + c0 + c16 + i * 4);
  }
  __syncthreads();
  int c = tid >> 2, r16 = (tid & 3) * 16;
  short8 o0, o1;
#pragma unroll
  for (int i = 0; i < 8; ++i) {
    o0[i] = f2bf(ld[r16 + i][c]);
    o1[i] = f2bf(ld[r16 + 8 + i][c]);
  }
  unsigned short* dp = d + (size_t)(c0 + c) * R + r0 + r16;
  *(short8*)(dp) = o0;
  *(short8*)(dp + 8) = o1;
}

// ---------------------------------------------------------------------------
// prep_all: [0,4096) src->bf16 | [4096,4864) WqkvT | [4864,4876) bqkv |
//           [4876,5132) WoT
// ---------------------------------------------------------------------------
__global__ __launch_bounds__(256) void prep_all(
    const float* __restrict__ src,
    const float* __restrict__ Wq, const float* __restrict__ Wk,
    const float* __restrict__ Wv,
    const float* __restrict__ bq, const float* __restrict__ bk,
    const float* __restrict__ bv, const float* __restrict__ Wo,
    unsigned short* __restrict__ srcb, unsigned short* __restrict__ wqkvT,
    float* __restrict__ bqkv, unsigned short* __restrict__ woT) {
  __shared__ float ld[64][68];
  const int bid = blockIdx.x, tid = threadIdx.x;
  if (bid < 4096) {
    int i8 = (bid * 256 + tid) * 8;
    float4 a = *(const float4*)(src + i8);
    float4 b = *(const float4*)(src + i8 + 4);
    short8 o;
    o[0] = f2bf(a.x); o[1] = f2bf(a.y); o[2] = f2bf(a.z); o[3] = f2bf(a.w);
    o[4] = f2bf(b.x); o[5] = f2bf(b.y); o[6] = f2bf(b.z); o[7] = f2bf(b.w);
    *(short8*)(srcb + i8) = o;
  } else if (bid < 4864) {
    int idx = bid - 4096;
    int d0 = (idx & 15) * 64, h = (idx >> 4) & 15, z = idx >> 8;
    const float* W = (z == 0 ? Wq : z == 1 ? Wk : Wv) + (size_t)h * DD * DK;
    {
      int r = tid >> 2, c16 = (tid & 3) * 16;
#pragma unroll
      for (int i = 0; i < 4; ++i)
        *(float4*)(&ld[r][c16 + i * 4]) =
            *(const float4*)(W + (size_t)(d0 + r) * DK + c16 + i * 4);
    }
    __syncthreads();
    int dv = tid >> 2, d16 = (tid & 3) * 16;
    short8 o0, o1;
#pragma unroll
    for (int i = 0; i < 8; ++i) {
      o0[i] = f2bf(ld[d16 + i][dv]);
      o1[i] = f2bf(ld[d16 + 8 + i][dv]);
    }
    unsigned short* dst = wqkvT + (size_t)(z * 1024 + h * 64 + dv) * DD + d0 + d16;
    *(short8*)(dst) = o0;
    *(short8*)(dst + 8) = o1;
  } else if (bid < 4876) {
    int n = (bid - 4864) * 256 + tid;
    int z = n >> 10;
    const float* s = (z == 0 ? bq : z == 1 ? bk : bv);
    bqkv[n] = s[n & 1023];
  } else {
    int idx = bid - 4876;
    tr64(Wo, woT, 1024, 1024, (idx & 15) * 64, (idx >> 4) * 64, ld, tid);
  }
}

// ---------------------------------------------------------------------------
// prep2 (after QKV GEMM):
//  [0,2048)      kb[bh][t][dk] contiguous copy from qkv
//  [2048,4096)   vt[bh][dv][t] transpose from qkv
//  [4096,4608)   maskb = bf16(mask * -1e9)
//  [4608,5632)   w1T [4096,1024]
//  [5632,6656)   w2T [1024,4096]
// ---------------------------------------------------------------------------
__global__ __launch_bounds__(256) void prep2(
    const unsigned short* __restrict__ qkv, const float* __restrict__ mask,
    const float* __restrict__ W1, const float* __restrict__ W2,
    unsigned short* __restrict__ kbb, unsigned short* __restrict__ vtb,
    unsigned short* __restrict__ maskb, unsigned short* __restrict__ w1T,
    unsigned short* __restrict__ w2T) {
  __shared__ float ldf[64][68];
  const int bid = blockIdx.x, tid = threadIdx.x;
  if (bid < 2048) {
    // kb copy: tile of 64 t rows
    const int t0 = (bid & 15) * 64, h = (bid >> 4) & 15, b = bid >> 8;
    int row = tid >> 2, c = (tid & 3) * 16;
    const unsigned short* s = qkv + (size_t)(b * SS + t0 + row) * 3072 + 1024 + h * 64 + c;
    unsigned short* d = kbb + ((size_t)((b * HH + h) * SS + t0 + row)) * 64 + c;
    *(short8*)(d) = *(const short8*)(s);
    *(short8*)(d + 8) = *(const short8*)(s + 8);
  } else if (bid < 4096) {
    // vt transpose
    __shared__ unsigned short ld[64][72];
    const int i = bid - 2048;
    const int t0 = (i & 15) * 64, h = (i >> 4) & 15, b = i >> 8;
    {
      int r = tid >> 2, c16 = (tid & 3) * 16;
      const unsigned short* s = qkv + (size_t)(b * SS + t0 + r) * 3072 + 2048 + h * 64 + c16;
      *(short8*)(&ld[r][c16]) = *(const short8*)(s);
      *(short8*)(&ld[r][c16 + 8]) = *(const short8*)(s + 8);
    }
    __syncthreads();
    int dv = tid >> 2, t16 = (tid & 3) * 16;
    short8 o0, o1;
#pragma unroll
    for (int j = 0; j < 8; ++j) {
      o0[j] = (short)ld[t16 + j][dv];
      o1[j] = (short)ld[t16 + 8 + j][dv];
    }
    unsigned short* d = vtb + ((size_t)(b * HH + h) * DK + dv) * SS + t0 + t16;
    *(short8*)(d) = o0;
    *(short8*)(d + 8) = o1;
  } else if (bid < 4608) {
    int i8 = ((bid - 4096) * 256 + tid) * 8;
    float4 a = *(const float4*)(mask + i8);
    float4 b = *(const float4*)(mask + i8 + 4);
    short8 o;
    o[0] = f2bf(a.x * -1e9f); o[1] = f2bf(a.y * -1e9f);
    o[2] = f2bf(a.z * -1e9f); o[3] = f2bf(a.w * -1e9f);
    o[4] = f2bf(b.x * -1e9f); o[5] = f2bf(b.y * -1e9f);
    o[6] = f2bf(b.z * -1e9f); o[7] = f2bf(b.w * -1e9f);
    *(short8*)(maskb + i8) = o;
  } else if (bid < 5632) {
    int i = bid - 4608;
    tr64(W1, w1T, 1024, 4096, (i & 15) * 64, (i >> 4) * 64, ldf, tid);
  } else {
    int i = bid - 5632;
    tr64(W2, w2T, 4096, 1024, (i & 63) * 64, (i >> 6) * 64, ldf, tid);
  }
}

// ---------------------------------------------------------------------------
// bf16 MFMA GEMM (m97 structure), swapped operands -> b64 epilogue stores.
// ---------------------------------------------------------------------------
template <int RELU>
__global__ __launch_bounds__(256) void gemm_bf16(
    const unsigned short* __restrict__ A, const unsigned short* __restrict__ Bt,
    const float* __restrict__ bias, unsigned short* __restrict__ C,
    int M, int N, int K) {
  const int n0 = blockIdx.x * 128, m0 = blockIdx.y * 128;
  __shared__ __align__(16) unsigned short As[128 * 32];
  __shared__ __align__(16) unsigned short Bs[128 * 32];
  const int tid = threadIdx.x;
  const int wave = tid >> 6, lane = tid & 63;
  const int lm = lane & 15, quad = lane >> 4;
  const int wr = wave >> 1, wc = wave & 1;
  const int srow = lane >> 2;
  const int scol = (lane & 3) * 8;

  floatx4 acc[4][4] = {};

  for (int k0 = 0; k0 < K; k0 += 32) {
#pragma unroll
    for (int j = 0; j < 2; ++j) {
      int rr = wave * 32 + j * 16;
      gload_lds16(A + (size_t)(m0 + rr + srow) * K + k0 + scol, &As[rr * 32]);
      gload_lds16(Bt + (size_t)(n0 + rr + srow) * K + k0 + scol, &Bs[rr * 32]);
    }
    __syncthreads();
    short8 af[4], bf[4];
#pragma unroll
    for (int i = 0; i < 4; ++i)
      af[i] = *(const short8*)&As[(wr * 64 + i * 16 + lm) * 32 + quad * 8];
#pragma unroll
    for (int j = 0; j < 4; ++j)
      bf[j] = *(const short8*)&Bs[(wc * 64 + j * 16 + lm) * 32 + quad * 8];
#pragma unroll
    for (int i = 0; i < 4; ++i)
#pragma unroll
      for (int j = 0; j < 4; ++j)
        acc[i][j] = __builtin_amdgcn_mfma_f32_16x16x32_bf16(bf[j], af[i], acc[i][j], 0, 0, 0);
    __syncthreads();
  }

#pragma unroll
  for (int i = 0; i < 4; ++i) {
    const int row = m0 + wr * 64 + i * 16 + lm;
#pragma unroll
    for (int j = 0; j < 4; ++j) {
      const int c0 = n0 + wc * 64 + j * 16 + quad * 4;
      float4 bv = *(const float4*)(bias + c0);
      float bb[4] = {bv.x, bv.y, bv.z, bv.w};
      short4v o;
#pragma unroll
      for (int r = 0; r < 4; ++r) {
        float v = acc[i][j][r] + bb[r];
        if (RELU) v = fmaxf(v, 0.f);
        o[r] = f2bf(v);
      }
      *(short4v*)(C + (size_t)row * N + c0) = o;
    }
  }
}

// ---------------------------------------------------------------------------
// Flash attention: 1024 blocks (8 q-tiles x 16 h x 8 b, XCD-swizzled),
// 512 thr = 8 waves, each wave owns 16 q-rows. Per 64-t K-tile:
//   stage K[64t][64dk], V^T[64dv][64t], mask[128q][64t] via coalesced
//   global_load_lds with XOR chunk swizzle (slot(r,j') holds chunk j'^(r&7));
//   S-tile MFMA -> online softmax in regs (lane owns q-row lm; alpha is
//   lane-uniform) -> P via wave-private LDS -> PV MFMA into O^T[64dv][16q].
// ---------------------------------------------------------------------------
__global__ __launch_bounds__(512) void attention_flash(
    const unsigned short* __restrict__ qkv, const unsigned short* __restrict__ kb,
    const unsigned short* __restrict__ vt, const unsigned short* __restrict__ maskb,
    unsigned short* __restrict__ ctx) {
  const int flat = blockIdx.x;
  const int bh = (flat & 7) + 8 * (flat >> 6);       // all q-tiles of a bh on one XCD
  const int qt = (flat >> 3) & 7;
  const int b = bh >> 4, h = bh & 15;
  const int s0 = qt * 128;
  const int tid = threadIdx.x;
  const int wave = tid >> 6, lane = tid & 63;
  const int lm = lane & 15, quad = lane >> 4;

  __shared__ __align__(16) unsigned short Ks[64 * 64];     //  8 KB swizzled [t][dk]
  __shared__ __align__(16) unsigned short Vs[64 * 64];     //  8 KB swizzled [dv][t]
  __shared__ __align__(16) unsigned short Ms[128 * 64];    // 16 KB swizzled [q][t]
  __shared__ __align__(16) unsigned short Ps[8][16 * 72];  // 18 KB wave-private P

  // Q fragments (once): q-row = s0 + wave*16 + lm
  const unsigned short* qp = qkv + (size_t)(b * SS + s0 + wave * 16 + lm) * 3072 + h * 64;
  const short8 qa0 = *(const short8*)(qp + quad * 8);
  const short8 qa1 = *(const short8*)(qp + quad * 8 + 32);

  const unsigned short* kbase = kb + (size_t)bh * SS * DK;   // [t][dk]
  const unsigned short* vbase = vt + (size_t)bh * DK * SS;   // [dv][t]
  const unsigned short* mbase = maskb + (size_t)s0 * SS;     // [q][t]

  const int sr = lane >> 3, sj = lane & 7;   // staging row-in-8 / chunk
  float m_run = -3e38f, l_run = 0.f;
  floatx4 O[4] = {};

  for (int it = 0; it < 16; ++it) {
    const int t0 = it * 64;
    __syncthreads();   // previous compute done before tiles overwritten
    {
      // K: slots [wave*64, +64): r = wave*8+sr, chunk = sj^(r&7)
      int r = wave * 8 + sr;
      gload_lds16(kbase + (size_t)(t0 + r) * 64 + (size_t)(sj ^ (r & 7)) * 8,
                  (char*)Ks + wave * 1024);
      // V^T: r = dv
      gload_lds16(vbase + (size_t)r * SS + t0 + (size_t)(sj ^ (r & 7)) * 8,
                  (char*)Vs + wave * 1024);
      // mask: 2 slots per thread
      int q1 = wave * 8 + sr;
      gload_lds16(mbase + (size_t)q1 * SS + t0 + (size_t)(sj ^ (q1 & 7)) * 8,
                  (char*)Ms + wave * 1024);
      int q2 = 64 + wave * 8 + sr;
      gload_lds16(mbase + (size_t)q2 * SS + t0 + (size_t)(sj ^ (q2 & 7)) * 8,
                  (char*)Ms + 8192 + wave * 1024);
    }
    __syncthreads();

    // ---- S = K-tile x Q (D[t][q]); lane collects 16 t-values for q=lm ----
    float p[16];
    float mt = -3e38f;
    const int qr = wave * 16 + lm;
#pragma unroll
    for (int ts = 0; ts < 4; ++ts) {
      int r = ts * 16 + lm;
      short8 kf0 = *(const short8*)&Ks[(r * 8 + (quad ^ (r & 7))) * 8];
      short8 kf1 = *(const short8*)&Ks[(r * 8 + ((quad + 4) ^ (r & 7))) * 8];
      floatx4 c = {0.f, 0.f, 0.f, 0.f};
      c = __builtin_amdgcn_mfma_f32_16x16x32_bf16(kf0, qa0, c, 0, 0, 0);
      c = __builtin_amdgcn_mfma_f32_16x16x32_bf16(kf1, qa1, c, 0, 0, 0);
      int mj = (ts * 2 + (quad >> 1)) ^ (qr & 7);
      short4v mv = *(const short4v*)&Ms[(qr * 8 + mj) * 8 + (quad & 1) * 4];
#pragma unroll
      for (int r2 = 0; r2 < 4; ++r2) {
        float sv = c[r2] * 0.125f + bf2f((unsigned short)mv[r2]);
        p[ts * 4 + r2] = sv;
        mt = fmaxf(mt, sv);
      }
    }
    mt = fmaxf(mt, __shfl_xor(mt, 16));
    mt = fmaxf(mt, __shfl_xor(mt, 32));
    float mnew = fmaxf(m_run, mt);
    float alpha = __expf(m_run - mnew);
    float psum = 0.f;
#pragma unroll
    for (int i = 0; i < 16; ++i) { p[i] = __expf(p[i] - mnew); psum += p[i]; }
    psum += __shfl_xor(psum, 16);
    psum += __shfl_xor(psum, 32);
    l_run = l_run * alpha + psum;
    m_run = mnew;
#pragma unroll
    for (int d = 0; d < 4; ++d)
#pragma unroll
      for (int r2 = 0; r2 < 4; ++r2) O[d][r2] *= alpha;

    // ---- P -> wave-private LDS (row lm, t-contiguous) ----
    unsigned short* pw = &Ps[wave][lm * 72];
#pragma unroll
    for (int ts = 0; ts < 4; ++ts) {
      short4v pv4;
#pragma unroll
      for (int r2 = 0; r2 < 4; ++r2) pv4[r2] = f2bf(p[ts * 4 + r2]);
      *(short4v*)(pw + ts * 16 + quad * 4) = pv4;
    }

    // ---- PV: O^T[dv][q] += V^T-tile x P^T ----
#pragma unroll
    for (int ks = 0; ks < 2; ++ks) {
      short8 pf = *(const short8*)(pw + ks * 32 + quad * 8);
#pragma unroll
      for (int d = 0; d < 4; ++d) {
        int dv = d * 16 + lm;
        short8 vf = *(const short8*)&Vs[(dv * 8 + ((ks * 4 + quad) ^ (dv & 7))) * 8];
        O[d] = __builtin_amdgcn_mfma_f32_16x16x32_bf16(vf, pf, O[d], 0, 0, 0);
      }
    }
  }

  // ---- epilogue: normalize, store ctx[b, s0+qr, h*64+dv] ----
  const float inv = 1.f / l_run;
  unsigned short* cp = ctx + (size_t)(b * SS + s0 + wave * 16 + lm) * DD + h * 64;
#pragma unroll
  for (int d = 0; d < 4; ++d) {
    short4v o;
#pragma unroll
    for (int r2 = 0; r2 < 4; ++r2) o[r2] = f2bf(O[d][r2] * inv);
    *(short4v*)(cp + d * 16 + quad * 4) = o;
  }
}

// ---------------------------------------------------------------------------
// Residual + LayerNorm: out = LN(a + r) * w + b. One block per row (D=1024).
// ---------------------------------------------------------------------------
template <int A_BF16, int OUT_BF16>
__global__ __launch_bounds__(256) void residual_ln(
    const void* __restrict__ a_, const unsigned short* __restrict__ rr,
    const float* __restrict__ w, const float* __restrict__ bias,
    void* __restrict__ out_) {
  const int row = blockIdx.x;
  const int t = threadIdx.x;
  float x[4];
  if (A_BF16) {
    short4v va = *(const short4v*)((const unsigned short*)a_ + (size_t)row * DD + t * 4);
#pragma unroll
    for (int i = 0; i < 4; ++i) x[i] = bf2f((unsigned short)va[i]);
  } else {
    float4 va = *(const float4*)((const float*)a_ + (size_t)row * DD + t * 4);
    x[0] = va.x; x[1] = va.y; x[2] = va.z; x[3] = va.w;
  }
  {
    short4v vr = *(const short4v*)(rr + (size_t)row * DD + t * 4);
#pragma unroll
    for (int i = 0; i < 4; ++i) x[i] += bf2f((unsigned short)vr[i]);
  }
  float s = 0.f, ss = 0.f;
#pragma unroll
  for (int i = 0; i < 4; ++i) { s += x[i]; ss += x[i] * x[i]; }
#pragma unroll
  for (int o = 32; o > 0; o >>= 1) {
    s  += __shfl_down(s, o);
    ss += __shfl_down(ss, o);
  }
  __shared__ float2 sred[4];
  int wid = t >> 6;
  if ((t & 63) == 0) sred[wid] = make_float2(s, ss);
  __syncthreads();
  float st = 0.f, sst = 0.f;
#pragma unroll
  for (int i = 0; i < 4; ++i) { st += sred[i].x; sst += sred[i].y; }
  float mu  = st * (1.f / 1024.f);
  float var = sst * (1.f / 1024.f) - mu * mu;
  float rsq = rsqrtf(var + 1e-5f);
  float4 vw = *(const float4*)(w + t * 4);
  float4 vb = *(const float4*)(bias + t * 4);
  float o[4];
  o[0] = (x[0] - mu) * rsq * vw.x + vb.x;
  o[1] = (x[1] - mu) * rsq * vw.y + vb.y;
  o[2] = (x[2] - mu) * rsq * vw.z + vb.z;
  o[3] = (x[3] - mu) * rsq * vw.w + vb.w;
  if (OUT_BF16) {
    short4v ov;
#pragma unroll
    for (int i = 0; i < 4; ++i) ov[i] = f2bf(o[i]);
    *(short4v*)((unsigned short*)out_ + (size_t)row * DD + t * 4) = ov;
  } else {
    float4 ov = {o[0], o[1], o[2], o[3]};
    *(float4*)((float*)out_ + (size_t)row * DD + t * 4) = ov;
  }
}

// ---------------------------------------------------------------------------
extern "C" void kernel_launch(void* const* d_in, const int* in_sizes, int n_in,
                              void* d_out, int out_size, void* d_ws, size_t ws_size,
                              hipStream_t stream) {
  const float* src  = (const float*)d_in[0];
  const float* mask = (const float*)d_in[1];
  const float* Wq = (const float*)d_in[2];  const float* bq = (const float*)d_in[3];
  const float* Wk = (const float*)d_in[4];  const float* bk = (const float*)d_in[5];
  const float* Wv = (const float*)d_in[6];  const float* bv = (const float*)d_in[7];
  const float* Wo = (const float*)d_in[8];  const float* bo = (const float*)d_in[9];
  const float* ln1w = (const float*)d_in[10]; const float* ln1b = (const float*)d_in[11];
  const float* W1 = (const float*)d_in[12]; const float* b1 = (const float*)d_in[13];
  const float* W2 = (const float*)d_in[14]; const float* b2 = (const float*)d_in[15];
  const float* ln2w = (const float*)d_in[16]; const float* ln2b = (const float*)d_in[17];
  float* out = (float*)d_out;

  // Workspace (total 125,841,408 B, same as proven):
  //  [  0, 48M) qkv           -> h1 [M,4096] spans [0,64M) after attention
  //  [ 48, 64M) vtb [bh,dv,t]
  //  [ 64, 80M) kbb [bh,t,dk] -> attn_out (after attention) -> ffn (after LN1)
  //  [ 80, 96M) ctxb          -> xb
  //  [ 96,112M) srcb          -> w1T@96 + w2T@104 (prep2, srcb dead)
  //  [112,118M) wqkvT         -> maskb@112 (prep2, wqkvT dead)
  //  [118,120M) woT
  //  [120M+..)  bqkv
  const size_t NEED = 125841408;
  if (ws_size < NEED) return;

  char* ws = (char*)d_ws;
  unsigned short* qkv   = (unsigned short*)(ws);
  unsigned short* vtb   = (unsigned short*)(ws + 50331648);
  unsigned short* kbb   = (unsigned short*)(ws + 67108864);
  unsigned short* ctxb  = (unsigned short*)(ws + 83886080);
  unsigned short* srcb  = (unsigned short*)(ws + 100663296);
  unsigned short* w1T   = (unsigned short*)(ws + 100663296);  // [4096,1024]
  unsigned short* w2T   = (unsigned short*)(ws + 109051904);  // [1024,4096]
  unsigned short* wqkvT = (unsigned short*)(ws + 117440512);  // [3072,1024]
  unsigned short* maskb = (unsigned short*)(ws + 117440512);  // [S,S] bf16
  unsigned short* woT   = (unsigned short*)(ws + 123731968);  // [1024,1024]
  float*          bqkv  = (float*)(ws + 125829120);           // [3072]
  unsigned short* h1       = qkv;                             // [M,4096] = [0,64M)
  unsigned short* attn_out = kbb;
  unsigned short* xb       = ctxb;
  unsigned short* ffn      = kbb;

  prep_all<<<5132, 256, 0, stream>>>(src, Wq, Wk, Wv, bq, bk, bv, Wo,
                                     srcb, wqkvT, bqkv, woT);
  gemm_bf16<0><<<dim3(3072 / 128, MM / 128), 256, 0, stream>>>(srcb, wqkvT, bqkv, qkv, MM, 3072, DD);
  prep2<<<6656, 256, 0, stream>>>(qkv, mask, W1, W2, kbb, vtb, maskb, w1T, w2T);
  attention_flash<<<1024, 512, 0, stream>>>(qkv, kbb, vtb, maskb, ctxb);
  gemm_bf16<0><<<dim3(DD / 128, MM / 128), 256, 0, stream>>>(ctxb, woT, bo, attn_out, MM, DD, DD);
  residual_ln<0, 1><<<MM, 256, 0, stream>>>(src, attn_out, ln1w, ln1b, xb);
  gemm_bf16<1><<<dim3(FF / 128, MM / 128), 256, 0, stream>>>(xb, w1T, b1, h1, MM, FF, DD);
  gemm_bf16<0><<<dim3(DD / 128, MM / 128), 256, 0, stream>>>(h1, w2T, b2, ffn, MM, DD, FF);
  residual_ln<1, 0><<<MM, 256, 0, stream>>>(xb, ffn, ln2w, ln2b, out);
}